// Round 1
// baseline (2208.568 us; speedup 1.0000x reference)
//
#include <hip/hip_runtime.h>

#define N_NODES 100000
#define N_EDGES 1600000
// IN=64, HID=64, OUT=32

// ---------------- edge kernel 1: agg1[dst] += x[src], deg[dst] += 1 ----------
// 16 threads per edge, each handles 4 contiguous dims via float4 gather.
__global__ __launch_bounds__(256) void edge_agg1(
    const int* __restrict__ ei, const float* __restrict__ x,
    float* __restrict__ agg1, float* __restrict__ deg)
{
    int t = blockIdx.x * 256 + threadIdx.x;
    int e = t >> 4;
    if (e >= N_EDGES) return;
    int part = t & 15;
    int src = ei[e];
    int dst = ei[N_EDGES + e];
    float4 v = ((const float4*)(x + (size_t)src * 64))[part];
    float* a = agg1 + (size_t)dst * 64 + part * 4;
    unsafeAtomicAdd(a + 0, v.x);
    unsafeAtomicAdd(a + 1, v.y);
    unsafeAtomicAdd(a + 2, v.z);
    unsafeAtomicAdd(a + 3, v.w);
    if (part == 0) unsafeAtomicAdd(&deg[dst], 1.0f);
}

// ---------------- node kernel 1: h = relu(mean@W1l + x@W1r + b1l); t2 = h@W2l
__global__ __launch_bounds__(128) void node1(
    const float* __restrict__ x, const float* __restrict__ agg1,
    const float* __restrict__ deg,
    const float* __restrict__ W1l, const float* __restrict__ b1l,
    const float* __restrict__ W1r, const float* __restrict__ W2l,
    float* __restrict__ h, float* __restrict__ t2)
{
    int n = blockIdx.x * 128 + threadIdx.x;
    if (n >= N_NODES) return;
    float inv = 1.0f / fmaxf(deg[n], 1.0f);

    float acc[64];
#pragma unroll
    for (int j = 0; j < 64; j++) acc[j] = b1l[j];

    const float4* av = (const float4*)(agg1 + (size_t)n * 64);
    const float4* xv = (const float4*)(x + (size_t)n * 64);
    for (int kk = 0; kk < 16; kk++) {
        float4 a4 = av[kk];
        float4 x4 = xv[kk];
        float as[4] = {a4.x * inv, a4.y * inv, a4.z * inv, a4.w * inv};
        float xs[4] = {x4.x, x4.y, x4.z, x4.w};
#pragma unroll
        for (int u = 0; u < 4; u++) {
            int k = kk * 4 + u;
            const float* wl = W1l + k * 64;
            const float* wr = W1r + k * 64;
#pragma unroll
            for (int j = 0; j < 64; j++)
                acc[j] += as[u] * wl[j] + xs[u] * wr[j];
        }
    }
#pragma unroll
    for (int j = 0; j < 64; j++) acc[j] = fmaxf(acc[j], 0.0f);

    float4* hv = (float4*)(h + (size_t)n * 64);
#pragma unroll
    for (int q = 0; q < 16; q++)
        hv[q] = make_float4(acc[4*q], acc[4*q+1], acc[4*q+2], acc[4*q+3]);

    // t2 = h @ W2l  (64 -> 32), bias added later in node2 path via b2l? No:
    // b2l is added once per node in node2. Here pure matmul.
    float acc2[32];
#pragma unroll
    for (int j = 0; j < 32; j++) acc2[j] = 0.0f;
    for (int k = 0; k < 64; k++) {
        float hk = acc[k];
        const float* w = W2l + k * 32;
#pragma unroll
        for (int j = 0; j < 32; j++) acc2[j] += hk * w[j];
    }
    float4* t2v = (float4*)(t2 + (size_t)n * 32);
#pragma unroll
    for (int q = 0; q < 8; q++)
        t2v[q] = make_float4(acc2[4*q], acc2[4*q+1], acc2[4*q+2], acc2[4*q+3]);
}

// ---------------- edge kernel 2: agg2[dst] += t2[src] (32 dims) -------------
__global__ __launch_bounds__(256) void edge_agg2(
    const int* __restrict__ ei, const float* __restrict__ t2,
    float* __restrict__ agg2)
{
    int t = blockIdx.x * 256 + threadIdx.x;
    int e = t >> 3;
    if (e >= N_EDGES) return;
    int part = t & 7;
    int src = ei[e];
    int dst = ei[N_EDGES + e];
    float4 v = ((const float4*)(t2 + (size_t)src * 32))[part];
    float* a = agg2 + (size_t)dst * 32 + part * 4;
    unsafeAtomicAdd(a + 0, v.x);
    unsafeAtomicAdd(a + 1, v.y);
    unsafeAtomicAdd(a + 2, v.z);
    unsafeAtomicAdd(a + 3, v.w);
}

// ---------------- node kernel 2: out = agg2/deg + h@W2r + b2l ---------------
__global__ __launch_bounds__(128) void node2(
    const float* __restrict__ h, const float* __restrict__ agg2,
    const float* __restrict__ deg,
    const float* __restrict__ W2r, const float* __restrict__ b2l,
    float* __restrict__ out)
{
    int n = blockIdx.x * 128 + threadIdx.x;
    if (n >= N_NODES) return;
    float inv = 1.0f / fmaxf(deg[n], 1.0f);

    float acc[32];
    const float4* gv = (const float4*)(agg2 + (size_t)n * 32);
#pragma unroll
    for (int q = 0; q < 8; q++) {
        float4 g4 = gv[q];
        acc[4*q+0] = b2l[4*q+0] + g4.x * inv;
        acc[4*q+1] = b2l[4*q+1] + g4.y * inv;
        acc[4*q+2] = b2l[4*q+2] + g4.z * inv;
        acc[4*q+3] = b2l[4*q+3] + g4.w * inv;
    }
    const float4* hv = (const float4*)(h + (size_t)n * 64);
    for (int kk = 0; kk < 16; kk++) {
        float4 h4 = hv[kk];
        float hs[4] = {h4.x, h4.y, h4.z, h4.w};
#pragma unroll
        for (int u = 0; u < 4; u++) {
            const float* w = W2r + (kk * 4 + u) * 32;
#pragma unroll
            for (int j = 0; j < 32; j++) acc[j] += hs[u] * w[j];
        }
    }
    float4* ov = (float4*)(out + (size_t)n * 32);
#pragma unroll
    for (int q = 0; q < 8; q++)
        ov[q] = make_float4(acc[4*q], acc[4*q+1], acc[4*q+2], acc[4*q+3]);
}

extern "C" void kernel_launch(void* const* d_in, const int* in_sizes, int n_in,
                              void* d_out, int out_size, void* d_ws, size_t ws_size,
                              hipStream_t stream) {
    const float* x   = (const float*)d_in[0];
    const int*   ei  = (const int*)d_in[1];   // int32 per harness convention
    const float* W1l = (const float*)d_in[2];
    const float* b1l = (const float*)d_in[3];
    const float* W1r = (const float*)d_in[4];
    const float* W2l = (const float*)d_in[5];
    const float* b2l = (const float*)d_in[6];
    const float* W2r = (const float*)d_in[7];
    float* out = (float*)d_out;

    float* ws = (float*)d_ws;
    const size_t N = N_NODES;
    // layout: [deg N][agg1 64N][agg2 32N][h 64N][t2 32N]  = 193N floats ~77MB
    float* deg  = ws;
    float* agg1 = ws + N;
    float* agg2 = ws + 65 * N;
    float* h    = ws + 97 * N;
    float* t2   = ws + 161 * N;

    // zero deg + agg1 + agg2 in one shot (97N floats)
    hipMemsetAsync(ws, 0, 97 * N * sizeof(float), stream);

    edge_agg1<<<(N_EDGES * 16 + 255) / 256, 256, 0, stream>>>(ei, x, agg1, deg);
    node1<<<(N_NODES + 127) / 128, 128, 0, stream>>>(x, agg1, deg, W1l, b1l, W1r, W2l, h, t2);
    edge_agg2<<<(N_EDGES * 8 + 255) / 256, 256, 0, stream>>>(ei, t2, agg2);
    node2<<<(N_NODES + 127) / 128, 128, 0, stream>>>(h, agg2, deg, W2r, b2l, out);
}

// Round 2
// 553.399 us; speedup vs baseline: 3.9909x; 3.9909x over previous
//
#include <hip/hip_runtime.h>

#define N_NODES 100000
#define N_EDGES 1600000
#define N_SCAN_BLOCKS ((N_NODES + 255) / 256)   // 391

// ============ CSR construction (counting sort by dst) ============

__global__ __launch_bounds__(256) void k_hist(const int* __restrict__ ei,
                                              int* __restrict__ cnt)
{
    int e = blockIdx.x * 256 + threadIdx.x;
    if (e >= N_EDGES) return;
    atomicAdd(&cnt[ei[N_EDGES + e]], 1);
}

__global__ __launch_bounds__(256) void k_scan_block(const int* __restrict__ cnt,
                                                    int* __restrict__ row_start,
                                                    int* __restrict__ partial)
{
    __shared__ int s[256];
    int i = blockIdx.x * 256 + threadIdx.x;
    int v = (i < N_NODES) ? cnt[i] : 0;
    s[threadIdx.x] = v;
    __syncthreads();
    for (int off = 1; off < 256; off <<= 1) {
        int t = (threadIdx.x >= off) ? s[threadIdx.x - off] : 0;
        __syncthreads();
        s[threadIdx.x] += t;
        __syncthreads();
    }
    if (i < N_NODES) row_start[i] = s[threadIdx.x] - v;   // exclusive
    if (threadIdx.x == 255) partial[blockIdx.x] = s[255]; // block total
}

__global__ __launch_bounds__(512) void k_scan_top(int* __restrict__ partial)
{
    __shared__ int s[512];
    int v = (threadIdx.x < N_SCAN_BLOCKS) ? partial[threadIdx.x] : 0;
    s[threadIdx.x] = v;
    __syncthreads();
    for (int off = 1; off < 512; off <<= 1) {
        int t = (threadIdx.x >= off) ? s[threadIdx.x - off] : 0;
        __syncthreads();
        s[threadIdx.x] += t;
        __syncthreads();
    }
    if (threadIdx.x < N_SCAN_BLOCKS) partial[threadIdx.x] = s[threadIdx.x] - v;
}

__global__ __launch_bounds__(256) void k_scan_add(int* __restrict__ row_start,
                                                 const int* __restrict__ partial,
                                                 int* __restrict__ cursor)
{
    int i = blockIdx.x * 256 + threadIdx.x;
    if (i < N_NODES) {
        int rs = row_start[i] + partial[i >> 8];
        row_start[i] = rs;
        cursor[i] = rs;
    }
    if (i == 0) row_start[N_NODES] = N_EDGES;
}

__global__ __launch_bounds__(256) void k_scatter(const int* __restrict__ ei,
                                                 int* __restrict__ cursor,
                                                 int* __restrict__ sorted_src)
{
    int e = blockIdx.x * 256 + threadIdx.x;
    if (e >= N_EDGES) return;
    int dst = ei[N_EDGES + e];
    int pos = atomicAdd(&cursor[dst], 1);
    sorted_src[pos] = ei[e];
}

// ============ aggregation: gather-reduce over CSR (no float atomics) ========

// one 64-lane wave per node, lane = dim
__global__ __launch_bounds__(256) void k_agg1(const int* __restrict__ row_start,
                                              const int* __restrict__ sorted_src,
                                              const float* __restrict__ x,
                                              float* __restrict__ agg1)
{
    int node = blockIdx.x * 4 + (threadIdx.x >> 6);
    if (node >= N_NODES) return;
    int d = threadIdx.x & 63;
    int beg = row_start[node], end = row_start[node + 1];
    float a0 = 0.0f, a1 = 0.0f;
    int idx = beg;
    for (; idx + 2 <= end; idx += 2) {
        int s0 = sorted_src[idx];
        int s1 = sorted_src[idx + 1];
        a0 += x[(size_t)s0 * 64 + d];
        a1 += x[(size_t)s1 * 64 + d];
    }
    if (idx < end) a0 += x[(size_t)sorted_src[idx] * 64 + d];
    agg1[(size_t)node * 64 + d] = a0 + a1;
}

// 32 lanes per node (two nodes per wave), lane = dim
__global__ __launch_bounds__(256) void k_agg2(const int* __restrict__ row_start,
                                              const int* __restrict__ sorted_src,
                                              const float* __restrict__ t2,
                                              float* __restrict__ agg2)
{
    int node = blockIdx.x * 8 + (threadIdx.x >> 5);
    if (node >= N_NODES) return;
    int d = threadIdx.x & 31;
    int beg = row_start[node], end = row_start[node + 1];
    float a0 = 0.0f, a1 = 0.0f;
    int idx = beg;
    for (; idx + 2 <= end; idx += 2) {
        int s0 = sorted_src[idx];
        int s1 = sorted_src[idx + 1];
        a0 += t2[(size_t)s0 * 32 + d];
        a1 += t2[(size_t)s1 * 32 + d];
    }
    if (idx < end) a0 += t2[(size_t)sorted_src[idx] * 32 + d];
    agg2[(size_t)node * 32 + d] = a0 + a1;
}

// ============ node kernels (dense transforms) ============

__global__ __launch_bounds__(128) void node1(
    const float* __restrict__ x, const float* __restrict__ agg1,
    const int* __restrict__ row_start,
    const float* __restrict__ W1l, const float* __restrict__ b1l,
    const float* __restrict__ W1r, const float* __restrict__ W2l,
    float* __restrict__ h, float* __restrict__ t2)
{
    int n = blockIdx.x * 128 + threadIdx.x;
    if (n >= N_NODES) return;
    float degf = (float)(row_start[n + 1] - row_start[n]);
    float inv = 1.0f / fmaxf(degf, 1.0f);

    float acc[64];
#pragma unroll
    for (int j = 0; j < 64; j++) acc[j] = b1l[j];

    const float4* av = (const float4*)(agg1 + (size_t)n * 64);
    const float4* xv = (const float4*)(x + (size_t)n * 64);
    for (int kk = 0; kk < 16; kk++) {
        float4 a4 = av[kk];
        float4 x4 = xv[kk];
        float as[4] = {a4.x * inv, a4.y * inv, a4.z * inv, a4.w * inv};
        float xs[4] = {x4.x, x4.y, x4.z, x4.w};
#pragma unroll
        for (int u = 0; u < 4; u++) {
            int k = kk * 4 + u;
            const float* wl = W1l + k * 64;
            const float* wr = W1r + k * 64;
#pragma unroll
            for (int j = 0; j < 64; j++)
                acc[j] += as[u] * wl[j] + xs[u] * wr[j];
        }
    }
#pragma unroll
    for (int j = 0; j < 64; j++) acc[j] = fmaxf(acc[j], 0.0f);

    float4* hv = (float4*)(h + (size_t)n * 64);
#pragma unroll
    for (int q = 0; q < 16; q++)
        hv[q] = make_float4(acc[4*q], acc[4*q+1], acc[4*q+2], acc[4*q+3]);

    // t2 = h @ W2l (64 -> 32); b2l added in node2
    float acc2[32];
#pragma unroll
    for (int j = 0; j < 32; j++) acc2[j] = 0.0f;
    for (int k = 0; k < 64; k++) {
        float hk = acc[k];
        const float* w = W2l + k * 32;
#pragma unroll
        for (int j = 0; j < 32; j++) acc2[j] += hk * w[j];
    }
    float4* t2v = (float4*)(t2 + (size_t)n * 32);
#pragma unroll
    for (int q = 0; q < 8; q++)
        t2v[q] = make_float4(acc2[4*q], acc2[4*q+1], acc2[4*q+2], acc2[4*q+3]);
}

__global__ __launch_bounds__(128) void node2(
    const float* __restrict__ h, const float* __restrict__ agg2,
    const int* __restrict__ row_start,
    const float* __restrict__ W2r, const float* __restrict__ b2l,
    float* __restrict__ out)
{
    int n = blockIdx.x * 128 + threadIdx.x;
    if (n >= N_NODES) return;
    float degf = (float)(row_start[n + 1] - row_start[n]);
    float inv = 1.0f / fmaxf(degf, 1.0f);

    float acc[32];
    const float4* gv = (const float4*)(agg2 + (size_t)n * 32);
#pragma unroll
    for (int q = 0; q < 8; q++) {
        float4 g4 = gv[q];
        acc[4*q+0] = b2l[4*q+0] + g4.x * inv;
        acc[4*q+1] = b2l[4*q+1] + g4.y * inv;
        acc[4*q+2] = b2l[4*q+2] + g4.z * inv;
        acc[4*q+3] = b2l[4*q+3] + g4.w * inv;
    }
    const float4* hv = (const float4*)(h + (size_t)n * 64);
    for (int kk = 0; kk < 16; kk++) {
        float4 h4 = hv[kk];
        float hs[4] = {h4.x, h4.y, h4.z, h4.w};
#pragma unroll
        for (int u = 0; u < 4; u++) {
            const float* w = W2r + (kk * 4 + u) * 32;
#pragma unroll
            for (int j = 0; j < 32; j++) acc[j] += hs[u] * w[j];
        }
    }
    float4* ov = (float4*)(out + (size_t)n * 32);
#pragma unroll
    for (int q = 0; q < 8; q++)
        ov[q] = make_float4(acc[4*q], acc[4*q+1], acc[4*q+2], acc[4*q+3]);
}

extern "C" void kernel_launch(void* const* d_in, const int* in_sizes, int n_in,
                              void* d_out, int out_size, void* d_ws, size_t ws_size,
                              hipStream_t stream) {
    const float* x   = (const float*)d_in[0];
    const int*   ei  = (const int*)d_in[1];
    const float* W1l = (const float*)d_in[2];
    const float* b1l = (const float*)d_in[3];
    const float* W1r = (const float*)d_in[4];
    const float* W2l = (const float*)d_in[5];
    const float* b2l = (const float*)d_in[6];
    const float* W2r = (const float*)d_in[7];
    float* out = (float*)d_out;

    const size_t N = N_NODES, E = N_EDGES;
    // int region
    int* wsi = (int*)d_ws;
    int* cursor     = wsi;                 // N   (cnt, then write cursors)
    int* row_start  = wsi + N;             // N+1
    int* partial    = wsi + 2 * N + 1;     // 512
    int* sorted_src = wsi + 2 * N + 513;   // E
    // float region (agg1 reused as agg2 after node1 consumes it)
    float* wsf = (float*)(wsi + 2 * N + 513 + E);
    float* agg1 = wsf;                     // 64N
    float* agg2 = wsf;                     // 32N (reuse of agg1's space)
    float* h    = wsf + 64 * N;            // 64N
    float* t2   = wsf + 128 * N;           // 32N
    // total: (2N+513+E)*4 + 160N*4  ~= 71.2 MB

    hipMemsetAsync(cursor, 0, N * sizeof(int), stream);
    k_hist      <<<(E + 255) / 256, 256, 0, stream>>>(ei, cursor);
    k_scan_block<<<N_SCAN_BLOCKS, 256, 0, stream>>>(cursor, row_start, partial);
    k_scan_top  <<<1, 512, 0, stream>>>(partial);
    k_scan_add  <<<N_SCAN_BLOCKS, 256, 0, stream>>>(row_start, partial, cursor);
    k_scatter   <<<(E + 255) / 256, 256, 0, stream>>>(ei, cursor, sorted_src);

    k_agg1<<<(int)(N / 4), 256, 0, stream>>>(row_start, sorted_src, x, agg1);
    node1 <<<(int)((N + 127) / 128), 128, 0, stream>>>(x, agg1, row_start,
                                                       W1l, b1l, W1r, W2l, h, t2);
    k_agg2<<<(int)(N / 8), 256, 0, stream>>>(row_start, sorted_src, t2, agg2);
    node2 <<<(int)((N + 127) / 128), 128, 0, stream>>>(h, agg2, row_start,
                                                       W2r, b2l, out);
}